// Round 5
// baseline (257.751 us; speedup 1.0000x reference)
//
#include <hip/hip_runtime.h>
#include <math.h>

#define NAGENT 4096
#define TOPK 32
#define CANDCAP 2048

// ---------------------------------------------------------------------------
// Kernel 1: exact top-32 nearest neighbors. VERBATIM from R12 (PASSED).
// ---------------------------------------------------------------------------
__global__ __launch_bounds__(256) void topk_kernel(
    const float* __restrict__ states, int* __restrict__ idx_out)
{
    const int i = blockIdx.x;
    const int t = threadIdx.x;
    const int lane = t & 63;
    __shared__ unsigned int hist[1024];
    __shared__ unsigned int wsum[4];
    __shared__ unsigned long long cand[CANDCAP];
    __shared__ int ccount;
    __shared__ unsigned int cutB;

    #pragma unroll
    for (int u = 0; u < 4; ++u) hist[t + u * 256] = 0u;
    if (t == 0) ccount = 0;

    const float4 si = ((const float4*)states)[i];
    __syncthreads();

    unsigned int mybits[16];
    #pragma unroll
    for (int u = 0; u < 16; ++u) {
        int j = t + u * 256;
        float4 sj = ((const float4*)states)[j];
        float dx = __fsub_rn(si.x, sj.x);
        float dy = __fsub_rn(si.y, sj.y);
        float s  = __fadd_rn(__fadd_rn(__fmul_rn(dx, dx), __fmul_rn(dy, dy)), 1e-4f);
        float dv = sqrtf(s);
        mybits[u] = __float_as_uint(dv);
        unsigned int bin = (unsigned int)(dv * 256.0f);
        if (bin > 1023u) bin = 1023u;
        atomicAdd(&hist[bin], 1u);
    }
    __syncthreads();

    unsigned int h0 = hist[t * 4 + 0], h1 = hist[t * 4 + 1];
    unsigned int h2 = hist[t * 4 + 2], h3 = hist[t * 4 + 3];
    unsigned int v = h0 + h1 + h2 + h3;
    unsigned int inc = v;
    #pragma unroll
    for (int off = 1; off < 64; off <<= 1) {
        unsigned int u = __shfl_up(inc, off, 64);
        if (lane >= off) inc += u;
    }
    if (lane == 63) wsum[t >> 6] = inc;
    __syncthreads();
    unsigned int woff = 0;
    for (int w = 0; w < (t >> 6); ++w) woff += wsum[w];
    unsigned int incl = inc + woff;
    unsigned int exc  = incl - v;
    if (exc < TOPK && incl >= TOPK) {
        unsigned int cum = exc;
        unsigned int hh[4] = {h0, h1, h2, h3};
        int b = t * 4 + 3;
        #pragma unroll
        for (int q = 0; q < 4; ++q) {
            cum += hh[q];
            if (cum >= TOPK) { b = t * 4 + q; break; }
        }
        cutB = (unsigned int)b;
    }
    __syncthreads();

    const unsigned int B = cutB;
    #pragma unroll
    for (int u = 0; u < 16; ++u) {
        float dv = __uint_as_float(mybits[u]);
        unsigned int bin = (unsigned int)(dv * 256.0f);
        if (bin > 1023u) bin = 1023u;
        if (bin <= B) {
            int pos = atomicAdd(&ccount, 1);
            if (pos < CANDCAP)
                cand[pos] = ((unsigned long long)mybits[u] << 32)
                          | (unsigned int)(t + u * 256);
        }
    }
    __syncthreads();

    const int C = (ccount < CANDCAP) ? ccount : CANDCAP;
    for (int q = t; q < C; q += 256) {
        unsigned long long key = cand[q];
        int rank = 0;
        for (int r = 0; r < C; ++r) rank += (cand[r] < key) ? 1 : 0;
        if (rank < TOPK) idx_out[i * TOPK + rank] = (int)(key & 0xffffffffu);
    }
}

// ---------------------------------------------------------------------------
// DPP max helper: VALU-only cross-lane max step (no DS pipe).
// ---------------------------------------------------------------------------
template <int CTRL>
__device__ __forceinline__ float dpp_max_step(float x)
{
    int y = __builtin_amdgcn_update_dpp(0, __float_as_int(x), CTRL, 0xF, 0xF, true);
    return fmaxf(x, __int_as_float(y));
}

// ---------------------------------------------------------------------------
// Kernel 2 (fused) R18 = R17 with __launch_bounds__(256, 2). R17's (256,4)
// imposed a 64-VGPR cap on this toolchain -> h1reg[64] lived in SCRATCH ->
// 4096 VMEM reads per lane in the h2 loop (invisible in FETCH_SIZE: scratch
// hits L1/L2), VALUBusy 27%, 170 us. Empirical anchor: R15's (512,2) gave
// VGPR 84 with zero spill. With ~100 VGPR the occupancy stays 4 waves/SIMD
// (grid-limited: 1024 blocks = 4 blocks/CU). Everything else is the R17
// PASSED code, verbatim (raw-reshape flat staging, zero-LDS h2, DPP argmax).
// ---------------------------------------------------------------------------
__global__ __launch_bounds__(256, 2) void fused_kernel(
    const float* __restrict__ states, const float* __restrict__ goals,
    const float* __restrict__ W1,  const float* __restrict__ b1,
    const float* __restrict__ W2,  const float* __restrict__ b2,
    const float* __restrict__ Wd1, const float* __restrict__ bd1,
    const float* __restrict__ Wd2, const float* __restrict__ bd2,
    const float* __restrict__ Wd3, const float* __restrict__ bd3,
    const float* __restrict__ Wd4, const float* __restrict__ bd4,
    const int* __restrict__ idx_in, float* __restrict__ out)
{
    const int t = threadIdx.x;
    const int w = t >> 6;               // wave 0..3
    const int l = t & 63;
    const int pair  = w >> 1;           // agent pair 0..1
    const int obase = (w & 1) << 6;     // this wave's o-range start (0 or 64)
    const int half  = l >> 5;           // which agent of the pair
    const int fa    = pair * 2 + half;  // local agent 0..3
    const int g     = blockIdx.x * 4 + fa;
    const int p     = l & 31;           // neighbor slot owned by this lane

    __shared__ __attribute__((aligned(16))) float flat[4][160];   // 2.5 KB
    __shared__ __attribute__((aligned(16))) float featb[4][132];  // 2.1 KB
    __shared__ __attribute__((aligned(16))) float zpool[4][264];  // 4.2 KB

    // ---- gather: stage xk row-major [32][5] (both waves of a pair write
    //      identical values -- benign). Mask stays lane-private (raw p).
    int j = idx_in[g * TOPK + p];
    float4 sj = ((const float4*)states)[j];
    float4 si = ((const float4*)states)[g];
    float d0 = si.x - sj.x;
    float d1 = si.y - sj.y;
    float d2 = si.z - sj.z;
    float d3 = si.w - sj.w;
    float slf = (j == g) ? 1.0f : 0.0f;
    float dist = sqrtf(__fadd_rn(__fmul_rn(d0, d0), __fmul_rn(d1, d1)));
    float mask = (dist < 1.0f) ? 1.0f : 0.0f;

    flat[fa][p * 5 + 0] = d0;
    flat[fa][p * 5 + 1] = d1;
    flat[fa][p * 5 + 2] = d2;
    flat[fa][p * 5 + 3] = d3;
    flat[fa][p * 5 + 4] = slf;

    if (p < 4) {
        float2 gi = ((const float2*)goals)[g];
        float v = (p == 0) ? (si.x - gi.x)
                : (p == 1) ? (si.y - gi.y)
                : (p == 2) ? si.z : si.w;
        featb[fa][128 + p] = v;
    }
    __syncthreads();   // flat visible across the pair's two waves

    // ---- raw-reshape inputs for this position p (5 scrambled elements)
    float in5[5];
    #pragma unroll
    for (int f = 0; f < 5; ++f) in5[f] = flat[fa][f * 32 + p];

    // ---- h1: lane-private registers, W1/b1 via wave-uniform scalar loads
    float h1reg[64];
    #pragma unroll
    for (int c = 0; c < 64; ++c) {
        float acc = b1[c];
        #pragma unroll
        for (int f = 0; f < 5; ++f)
            acc += W1[c * 5 + f] * in5[f];     // f ascending: same order as R13
        h1reg[c] = fmaxf(acc, 0.0f);
    }

    // ---- h2 + argmax: o in [obase, obase+64); W2 row streams through SGPRs
    for (int oi = 0; oi < 64; ++oi) {
        const int o = obase + oi;
        const float* __restrict__ w2r = &W2[o * 64];
        float acc = 0.0f;
        #pragma unroll
        for (int c = 0; c < 64; ++c)
            acc += w2r[c] * h1reg[c];          // c ascending: same order as R13
        float val = fmaxf(acc + b2[o], 0.0f) * mask;

        // 32-lane max within agent half: 4 DPP steps (VALU) + 1 xor16 shuffle
        float m = val;
        m = dpp_max_step<0xB1>(m);    // quad_perm [1,0,3,2] : max over 2
        m = dpp_max_step<0x4E>(m);    // quad_perm [2,3,0,1] : max over 4
        m = dpp_max_step<0x141>(m);   // row_half_mirror     : max over 8
        m = dpp_max_step<0x140>(m);   // row_mirror          : max over 16
        m = fmaxf(m, __shfl_xor(m, 16, 64));   // max over 32 (stays in half)

        unsigned long long bal = __ballot(val == m);
        unsigned int bh = half ? (unsigned int)(bal >> 32) : (unsigned int)bal;
        float pb = (float)(__ffs(bh) - 1);     // first max = smallest p (jnp.argmax)
        if (p == 0) featb[fa][o] = pb;
    }

    __syncthreads();   // featb rows complete (both o-halves, goal feats)

    // ---- dense: wave w handles agent blockIdx.x*4 + w (R15 code, verbatim)
    float* z1s = &zpool[w][0];    // 64
    float* z2s = z1s + 64;        // 128
    float* z3s = z1s + 192;       // 64
    float* kvs = z1s + 256;       // 4
    const int gd = blockIdx.x * 4 + w;

    {
        float a0 = bd1[l];
        for (int k = 0; k < 33; ++k) {
            float4 wv = *(const float4*)&Wd1[l * 132 + 4 * k];
            float4 f0 = *(const float4*)&featb[w][4 * k];
            a0 += wv.x * f0.x; a0 += wv.y * f0.y; a0 += wv.z * f0.z; a0 += wv.w * f0.w;
        }
        z1s[l] = fmaxf(a0, 0.0f);
    }

    {
        float accA = bd2[l];
        float accB = bd2[l + 64];
        for (int k = 0; k < 16; ++k) {
            float4 wa = *(const float4*)&Wd2[l * 64 + 4 * k];
            float4 wb = *(const float4*)&Wd2[(l + 64) * 64 + 4 * k];
            float4 f0 = *(const float4*)&z1s[4 * k];
            accA += wa.x * f0.x; accA += wa.y * f0.y;
            accA += wa.z * f0.z; accA += wa.w * f0.w;
            accB += wb.x * f0.x; accB += wb.y * f0.y;
            accB += wb.z * f0.z; accB += wb.w * f0.w;
        }
        z2s[l]      = fmaxf(accA, 0.0f);
        z2s[l + 64] = fmaxf(accB, 0.0f);
    }

    {
        float a0 = bd3[l];
        for (int k = 0; k < 32; ++k) {
            float4 wv = *(const float4*)&Wd3[l * 128 + 4 * k];
            float4 f0 = *(const float4*)&z2s[4 * k];
            a0 += wv.x * f0.x; a0 += wv.y * f0.y; a0 += wv.z * f0.z; a0 += wv.w * f0.w;
        }
        z3s[l] = fmaxf(a0, 0.0f);
    }

    if (l < 4) {
        float acc = bd4[l];
        for (int c = 0; c < 64; ++c) acc += Wd4[l * 64 + c] * z3s[c];
        kvs[l] = 2.0f / (1.0f + expf(-acc)) + 0.2f;
    }
    if (l < 2) {
        float ka = kvs[2 * l + 0];
        float kb = kvs[2 * l + 1];
        float rel = featb[w][128 + l];
        float vel = featb[w][130 + l];
        out[gd * 2 + l] = -(ka * rel + kb * vel);
    }
}

extern "C" void kernel_launch(void* const* d_in, const int* in_sizes, int n_in,
                              void* d_out, int out_size, void* d_ws, size_t ws_size,
                              hipStream_t stream)
{
    const float* states = (const float*)d_in[0];
    const float* goals  = (const float*)d_in[1];
    const float* W1  = (const float*)d_in[2];
    const float* b1  = (const float*)d_in[3];
    const float* W2  = (const float*)d_in[4];
    const float* b2  = (const float*)d_in[5];
    const float* Wd1 = (const float*)d_in[6];
    const float* bd1 = (const float*)d_in[7];
    const float* Wd2 = (const float*)d_in[8];
    const float* bd2 = (const float*)d_in[9];
    const float* Wd3 = (const float*)d_in[10];
    const float* bd3 = (const float*)d_in[11];
    const float* Wd4 = (const float*)d_in[12];
    const float* bd4 = (const float*)d_in[13];

    int*   idx = (int*)d_ws;   // 512 KB
    float* out = (float*)d_out;

    topk_kernel<<<NAGENT, 256, 0, stream>>>(states, idx);
    fused_kernel<<<NAGENT / 4, 256, 0, stream>>>(states, goals, W1, b1, W2, b2,
                                                 Wd1, bd1, Wd2, bd2, Wd3, bd3,
                                                 Wd4, bd4, idx, out);
}

// Round 6
// 171.893 us; speedup vs baseline: 1.4995x; 1.4995x over previous
//
#include <hip/hip_runtime.h>
#include <math.h>

#define NAGENT 4096
#define TOPK 32
#define CANDCAP 2048

// ---------------------------------------------------------------------------
// Kernel 1: exact top-32 nearest neighbors. VERBATIM from R12 (PASSED).
// ---------------------------------------------------------------------------
__global__ __launch_bounds__(256) void topk_kernel(
    const float* __restrict__ states, int* __restrict__ idx_out)
{
    const int i = blockIdx.x;
    const int t = threadIdx.x;
    const int lane = t & 63;
    __shared__ unsigned int hist[1024];
    __shared__ unsigned int wsum[4];
    __shared__ unsigned long long cand[CANDCAP];
    __shared__ int ccount;
    __shared__ unsigned int cutB;

    #pragma unroll
    for (int u = 0; u < 4; ++u) hist[t + u * 256] = 0u;
    if (t == 0) ccount = 0;

    const float4 si = ((const float4*)states)[i];
    __syncthreads();

    unsigned int mybits[16];
    #pragma unroll
    for (int u = 0; u < 16; ++u) {
        int j = t + u * 256;
        float4 sj = ((const float4*)states)[j];
        float dx = __fsub_rn(si.x, sj.x);
        float dy = __fsub_rn(si.y, sj.y);
        float s  = __fadd_rn(__fadd_rn(__fmul_rn(dx, dx), __fmul_rn(dy, dy)), 1e-4f);
        float dv = sqrtf(s);
        mybits[u] = __float_as_uint(dv);
        unsigned int bin = (unsigned int)(dv * 256.0f);
        if (bin > 1023u) bin = 1023u;
        atomicAdd(&hist[bin], 1u);
    }
    __syncthreads();

    unsigned int h0 = hist[t * 4 + 0], h1 = hist[t * 4 + 1];
    unsigned int h2 = hist[t * 4 + 2], h3 = hist[t * 4 + 3];
    unsigned int v = h0 + h1 + h2 + h3;
    unsigned int inc = v;
    #pragma unroll
    for (int off = 1; off < 64; off <<= 1) {
        unsigned int u = __shfl_up(inc, off, 64);
        if (lane >= off) inc += u;
    }
    if (lane == 63) wsum[t >> 6] = inc;
    __syncthreads();
    unsigned int woff = 0;
    for (int w = 0; w < (t >> 6); ++w) woff += wsum[w];
    unsigned int incl = inc + woff;
    unsigned int exc  = incl - v;
    if (exc < TOPK && incl >= TOPK) {
        unsigned int cum = exc;
        unsigned int hh[4] = {h0, h1, h2, h3};
        int b = t * 4 + 3;
        #pragma unroll
        for (int q = 0; q < 4; ++q) {
            cum += hh[q];
            if (cum >= TOPK) { b = t * 4 + q; break; }
        }
        cutB = (unsigned int)b;
    }
    __syncthreads();

    const unsigned int B = cutB;
    #pragma unroll
    for (int u = 0; u < 16; ++u) {
        float dv = __uint_as_float(mybits[u]);
        unsigned int bin = (unsigned int)(dv * 256.0f);
        if (bin > 1023u) bin = 1023u;
        if (bin <= B) {
            int pos = atomicAdd(&ccount, 1);
            if (pos < CANDCAP)
                cand[pos] = ((unsigned long long)mybits[u] << 32)
                          | (unsigned int)(t + u * 256);
        }
    }
    __syncthreads();

    const int C = (ccount < CANDCAP) ? ccount : CANDCAP;
    for (int q = t; q < C; q += 256) {
        unsigned long long key = cand[q];
        int rank = 0;
        for (int r = 0; r < C; ++r) rank += (cand[r] < key) ? 1 : 0;
        if (rank < TOPK) idx_out[i * TOPK + rank] = (int)(key & 0xffffffffu);
    }
}

// ---------------------------------------------------------------------------
// DPP max helper: VALU-only cross-lane max step (no DS pipe).
// ---------------------------------------------------------------------------
template <int CTRL>
__device__ __forceinline__ float dpp_max_step(float x)
{
    int y = __builtin_amdgcn_update_dpp(0, __float_as_int(x), CTRL, 0xF, 0xF, true);
    return fmaxf(x, __int_as_float(y));
}

// ---------------------------------------------------------------------------
// Kernel 2 (fused) R19: same math as R17/R18 (PASSED, absmax 0.0) with two
// mechanical fixes for the scratch-spill diagnosis:
//  (1) h1 lives in 16 NAMED float4 variables (H0..H15) built by macro.
//      R17/R18's h1reg[64] alloca was never SROA-promoted (inner-loop unroll
//      happens after the last SROA pass -> array stayed in scratch -> 4096
//      scratch reads/lane in h2 -> VALUBusy 27%, VGPR "64"). Named vars are
//      mem2reg-promoted unconditionally.
//  (2) obase through __builtin_amdgcn_readfirstlane: threadIdx>>6 is not
//      workgroup-uniform, so &W2[o*64] was treated divergent (vector loads).
//      SGPR-by-construction o -> s_load row stream, v_fmac with SGPR operand,
//      zero VGPR cost for W2.
// Accumulation order per output (b1-first f-ascending h1; c-ascending single
// chain h2) is bitwise R13/R17. Plain __launch_bounds__(256) (topk precedent).
// ---------------------------------------------------------------------------
#define H1C(dst, c) { float acc_ = b1[c]; \
    acc_ += W1[(c) * 5 + 0] * i0; \
    acc_ += W1[(c) * 5 + 1] * i1; \
    acc_ += W1[(c) * 5 + 2] * i2; \
    acc_ += W1[(c) * 5 + 3] * i3; \
    acc_ += W1[(c) * 5 + 4] * i4; \
    dst = fmaxf(acc_, 0.0f); }
#define H1G(Hv, cb) { H1C(Hv.x, (cb) + 0) H1C(Hv.y, (cb) + 1) \
                      H1C(Hv.z, (cb) + 2) H1C(Hv.w, (cb) + 3) }
#define ACC4(Hv, kk) { float4 wv_ = w2r[kk]; \
    acc += wv_.x * Hv.x; acc += wv_.y * Hv.y; \
    acc += wv_.z * Hv.z; acc += wv_.w * Hv.w; }

__global__ __launch_bounds__(256) void fused_kernel(
    const float* __restrict__ states, const float* __restrict__ goals,
    const float* __restrict__ W1,  const float* __restrict__ b1,
    const float* __restrict__ W2,  const float* __restrict__ b2,
    const float* __restrict__ Wd1, const float* __restrict__ bd1,
    const float* __restrict__ Wd2, const float* __restrict__ bd2,
    const float* __restrict__ Wd3, const float* __restrict__ bd3,
    const float* __restrict__ Wd4, const float* __restrict__ bd4,
    const int* __restrict__ idx_in, float* __restrict__ out)
{
    const int t = threadIdx.x;
    const int w = t >> 6;               // wave 0..3
    const int l = t & 63;
    const int pair  = w >> 1;           // agent pair 0..1
    const int half  = l >> 5;           // which agent of the pair
    const int fa    = pair * 2 + half;  // local agent 0..3
    const int g     = blockIdx.x * 4 + fa;
    const int p     = l & 31;           // neighbor slot owned by this lane
    // wave-uniform o-range start (0 or 64), SGPR by construction:
    const int obase = __builtin_amdgcn_readfirstlane((w & 1) << 6);

    __shared__ __attribute__((aligned(16))) float flat[4][160];   // 2.5 KB
    __shared__ __attribute__((aligned(16))) float featb[4][132];  // 2.1 KB
    __shared__ __attribute__((aligned(16))) float zpool[4][264];  // 4.2 KB

    // ---- gather: stage xk row-major [32][5] (both waves of a pair write
    //      identical values -- benign). Mask stays lane-private (raw p).
    int j = idx_in[g * TOPK + p];
    float4 sj = ((const float4*)states)[j];
    float4 si = ((const float4*)states)[g];
    float d0 = si.x - sj.x;
    float d1 = si.y - sj.y;
    float d2 = si.z - sj.z;
    float d3 = si.w - sj.w;
    float slf = (j == g) ? 1.0f : 0.0f;
    float dist = sqrtf(__fadd_rn(__fmul_rn(d0, d0), __fmul_rn(d1, d1)));
    float mask = (dist < 1.0f) ? 1.0f : 0.0f;

    flat[fa][p * 5 + 0] = d0;
    flat[fa][p * 5 + 1] = d1;
    flat[fa][p * 5 + 2] = d2;
    flat[fa][p * 5 + 3] = d3;
    flat[fa][p * 5 + 4] = slf;

    if (p < 4) {
        float2 gi = ((const float2*)goals)[g];
        float v = (p == 0) ? (si.x - gi.x)
                : (p == 1) ? (si.y - gi.y)
                : (p == 2) ? si.z : si.w;
        featb[fa][128 + p] = v;
    }
    __syncthreads();   // flat visible across the pair's two waves

    // ---- raw-reshape inputs for this position p (5 scrambled elements)
    float i0 = flat[fa][0 * 32 + p];
    float i1 = flat[fa][1 * 32 + p];
    float i2 = flat[fa][2 * 32 + p];
    float i3 = flat[fa][3 * 32 + p];
    float i4 = flat[fa][4 * 32 + p];

    // ---- h1: 16 named float4 registers (guaranteed promotion)
    float4 H0, H1, H2, H3, H4, H5, H6, H7, H8, H9, H10, H11, H12, H13, H14, H15;
    H1G(H0,   0) H1G(H1,   4) H1G(H2,   8) H1G(H3,  12)
    H1G(H4,  16) H1G(H5,  20) H1G(H6,  24) H1G(H7,  28)
    H1G(H8,  32) H1G(H9,  36) H1G(H10, 40) H1G(H11, 44)
    H1G(H12, 48) H1G(H13, 52) H1G(H14, 56) H1G(H15, 60)

    // ---- h2 + argmax: o in [obase, obase+64); W2 rows via s_load (uniform o)
    for (int oi = 0; oi < 64; ++oi) {
        const int o = obase + oi;
        const float4* __restrict__ w2r = (const float4*)&W2[o * 64];
        float acc = 0.0f;
        ACC4(H0,   0) ACC4(H1,   1) ACC4(H2,   2) ACC4(H3,   3)
        ACC4(H4,   4) ACC4(H5,   5) ACC4(H6,   6) ACC4(H7,   7)
        ACC4(H8,   8) ACC4(H9,   9) ACC4(H10, 10) ACC4(H11, 11)
        ACC4(H12, 12) ACC4(H13, 13) ACC4(H14, 14) ACC4(H15, 15)
        float val = fmaxf(acc + b2[o], 0.0f) * mask;

        // 32-lane max within agent half: 4 DPP steps (VALU) + 1 xor16 shuffle
        float m = val;
        m = dpp_max_step<0xB1>(m);    // quad_perm [1,0,3,2] : max over 2
        m = dpp_max_step<0x4E>(m);    // quad_perm [2,3,0,1] : max over 4
        m = dpp_max_step<0x141>(m);   // row_half_mirror     : max over 8
        m = dpp_max_step<0x140>(m);   // row_mirror          : max over 16
        m = fmaxf(m, __shfl_xor(m, 16, 64));   // max over 32 (stays in half)

        unsigned long long bal = __ballot(val == m);
        unsigned int bh = half ? (unsigned int)(bal >> 32) : (unsigned int)bal;
        float pb = (float)(__ffs(bh) - 1);     // first max = smallest p (jnp.argmax)
        if (p == 0) featb[fa][o] = pb;
    }

    __syncthreads();   // featb rows complete (both o-halves, goal feats)

    // ---- dense: wave w handles agent blockIdx.x*4 + w (R15 code, verbatim)
    float* z1s = &zpool[w][0];    // 64
    float* z2s = z1s + 64;        // 128
    float* z3s = z1s + 192;       // 64
    float* kvs = z1s + 256;       // 4
    const int gd = blockIdx.x * 4 + w;

    {
        float a0 = bd1[l];
        for (int k = 0; k < 33; ++k) {
            float4 wv = *(const float4*)&Wd1[l * 132 + 4 * k];
            float4 f0 = *(const float4*)&featb[w][4 * k];
            a0 += wv.x * f0.x; a0 += wv.y * f0.y; a0 += wv.z * f0.z; a0 += wv.w * f0.w;
        }
        z1s[l] = fmaxf(a0, 0.0f);
    }

    {
        float accA = bd2[l];
        float accB = bd2[l + 64];
        for (int k = 0; k < 16; ++k) {
            float4 wa = *(const float4*)&Wd2[l * 64 + 4 * k];
            float4 wb = *(const float4*)&Wd2[(l + 64) * 64 + 4 * k];
            float4 f0 = *(const float4*)&z1s[4 * k];
            accA += wa.x * f0.x; accA += wa.y * f0.y;
            accA += wa.z * f0.z; accA += wa.w * f0.w;
            accB += wb.x * f0.x; accB += wb.y * f0.y;
            accB += wb.z * f0.z; accB += wb.w * f0.w;
        }
        z2s[l]      = fmaxf(accA, 0.0f);
        z2s[l + 64] = fmaxf(accB, 0.0f);
    }

    {
        float a0 = bd3[l];
        for (int k = 0; k < 32; ++k) {
            float4 wv = *(const float4*)&Wd3[l * 128 + 4 * k];
            float4 f0 = *(const float4*)&z2s[4 * k];
            a0 += wv.x * f0.x; a0 += wv.y * f0.y; a0 += wv.z * f0.z; a0 += wv.w * f0.w;
        }
        z3s[l] = fmaxf(a0, 0.0f);
    }

    if (l < 4) {
        float acc = bd4[l];
        for (int c = 0; c < 64; ++c) acc += Wd4[l * 64 + c] * z3s[c];
        kvs[l] = 2.0f / (1.0f + expf(-acc)) + 0.2f;
    }
    if (l < 2) {
        float ka = kvs[2 * l + 0];
        float kb = kvs[2 * l + 1];
        float rel = featb[w][128 + l];
        float vel = featb[w][130 + l];
        out[gd * 2 + l] = -(ka * rel + kb * vel);
    }
}

extern "C" void kernel_launch(void* const* d_in, const int* in_sizes, int n_in,
                              void* d_out, int out_size, void* d_ws, size_t ws_size,
                              hipStream_t stream)
{
    const float* states = (const float*)d_in[0];
    const float* goals  = (const float*)d_in[1];
    const float* W1  = (const float*)d_in[2];
    const float* b1  = (const float*)d_in[3];
    const float* W2  = (const float*)d_in[4];
    const float* b2  = (const float*)d_in[5];
    const float* Wd1 = (const float*)d_in[6];
    const float* bd1 = (const float*)d_in[7];
    const float* Wd2 = (const float*)d_in[8];
    const float* bd2 = (const float*)d_in[9];
    const float* Wd3 = (const float*)d_in[10];
    const float* bd3 = (const float*)d_in[11];
    const float* Wd4 = (const float*)d_in[12];
    const float* bd4 = (const float*)d_in[13];

    int*   idx = (int*)d_ws;   // 512 KB
    float* out = (float*)d_out;

    topk_kernel<<<NAGENT, 256, 0, stream>>>(states, idx);
    fused_kernel<<<NAGENT / 4, 256, 0, stream>>>(states, goals, W1, b1, W2, b2,
                                                 Wd1, bd1, Wd2, bd2, Wd3, bd3,
                                                 Wd4, bd4, idx, out);
}

// Round 7
// 162.683 us; speedup vs baseline: 1.5844x; 1.0566x over previous
//
#include <hip/hip_runtime.h>
#include <math.h>

#define NAGENT 4096
#define TOPK 32
#define CANDCAP 2048

// ---------------------------------------------------------------------------
// Kernel 1: exact top-32 nearest neighbors. R12 logic verbatim; two additions:
//  - idx_out is u16 (values < 4096) so workspace also fits W2^T
//  - block 0 publishes w2t[c*128+o] = W2[o*64+c] for the fused kernel
// ---------------------------------------------------------------------------
__global__ __launch_bounds__(256) void topk_kernel(
    const float* __restrict__ states, const float* __restrict__ W2,
    unsigned short* __restrict__ idx_out, float* __restrict__ w2t)
{
    const int i = blockIdx.x;
    const int t = threadIdx.x;
    const int lane = t & 63;
    __shared__ unsigned int hist[1024];
    __shared__ unsigned int wsum[4];
    __shared__ unsigned long long cand[CANDCAP];
    __shared__ int ccount;
    __shared__ unsigned int cutB;

    // ---- publish W2^T (one block; independent of the top-k work below)
    if (i == 0) {
        for (int e = t; e < 8192; e += 256) {
            int o = e & 127, c = e >> 7;
            w2t[c * 128 + o] = W2[o * 64 + c];   // writes coalesced in e
        }
    }

    #pragma unroll
    for (int u = 0; u < 4; ++u) hist[t + u * 256] = 0u;
    if (t == 0) ccount = 0;

    const float4 si = ((const float4*)states)[i];
    __syncthreads();

    unsigned int mybits[16];
    #pragma unroll
    for (int u = 0; u < 16; ++u) {
        int j = t + u * 256;
        float4 sj = ((const float4*)states)[j];
        float dx = __fsub_rn(si.x, sj.x);
        float dy = __fsub_rn(si.y, sj.y);
        float s  = __fadd_rn(__fadd_rn(__fmul_rn(dx, dx), __fmul_rn(dy, dy)), 1e-4f);
        float dv = sqrtf(s);
        mybits[u] = __float_as_uint(dv);
        unsigned int bin = (unsigned int)(dv * 256.0f);
        if (bin > 1023u) bin = 1023u;
        atomicAdd(&hist[bin], 1u);
    }
    __syncthreads();

    unsigned int h0 = hist[t * 4 + 0], h1 = hist[t * 4 + 1];
    unsigned int h2 = hist[t * 4 + 2], h3 = hist[t * 4 + 3];
    unsigned int v = h0 + h1 + h2 + h3;
    unsigned int inc = v;
    #pragma unroll
    for (int off = 1; off < 64; off <<= 1) {
        unsigned int u = __shfl_up(inc, off, 64);
        if (lane >= off) inc += u;
    }
    if (lane == 63) wsum[t >> 6] = inc;
    __syncthreads();
    unsigned int woff = 0;
    for (int w = 0; w < (t >> 6); ++w) woff += wsum[w];
    unsigned int incl = inc + woff;
    unsigned int exc  = incl - v;
    if (exc < TOPK && incl >= TOPK) {
        unsigned int cum = exc;
        unsigned int hh[4] = {h0, h1, h2, h3};
        int b = t * 4 + 3;
        #pragma unroll
        for (int q = 0; q < 4; ++q) {
            cum += hh[q];
            if (cum >= TOPK) { b = t * 4 + q; break; }
        }
        cutB = (unsigned int)b;
    }
    __syncthreads();

    const unsigned int B = cutB;
    #pragma unroll
    for (int u = 0; u < 16; ++u) {
        float dv = __uint_as_float(mybits[u]);
        unsigned int bin = (unsigned int)(dv * 256.0f);
        if (bin > 1023u) bin = 1023u;
        if (bin <= B) {
            int pos = atomicAdd(&ccount, 1);
            if (pos < CANDCAP)
                cand[pos] = ((unsigned long long)mybits[u] << 32)
                          | (unsigned int)(t + u * 256);
        }
    }
    __syncthreads();

    const int C = (ccount < CANDCAP) ? ccount : CANDCAP;
    for (int q = t; q < C; q += 256) {
        unsigned long long key = cand[q];
        int rank = 0;
        for (int r = 0; r < C; ++r) rank += (cand[r] < key) ? 1 : 0;
        if (rank < TOPK)
            idx_out[i * TOPK + rank] = (unsigned short)(key & 0xffffu);
    }
}

// ---------------------------------------------------------------------------
// Kernel 2 (fused) R20: R13's PROVEN h2 core (identical index math, identical
// accumulation order -> absmax 0.0) with W2 moved from LDS to an L2-resident
// transposed global buffer (w2t[c*128+o], pre-built by topk block 0):
//  - per-cc W2 reads become coalesced 256-B global float4 loads (the exact
//    pattern R13's dense phase compiled cleanly at 128 VGPR)
//  - LDS 77.3 KB -> 39.1 KB -> 4 blocks/CU; FAGB 8->4 (4 waves x 1 agent,
//    no rounds) -> grid 1024 = exactly 4 blocks/CU = 16 waves/CU = 4/SIMD,
//    double R13's latency hiding; DS pipe load halved.
//  - everything is wave-private; single barrier (w1s/b1s/b2s staging only).
// ---------------------------------------------------------------------------
__global__ __launch_bounds__(256) void fused_kernel(
    const float* __restrict__ states, const float* __restrict__ goals,
    const float* __restrict__ W1,  const float* __restrict__ b1,
    const float* __restrict__ w2t, const float* __restrict__ b2,
    const float* __restrict__ Wd1, const float* __restrict__ bd1,
    const float* __restrict__ Wd2, const float* __restrict__ bd2,
    const float* __restrict__ Wd3, const float* __restrict__ bd3,
    const float* __restrict__ Wd4, const float* __restrict__ bd4,
    const unsigned short* __restrict__ idx_in, float* __restrict__ out)
{
    const int t = threadIdx.x;
    const int w = t >> 6;               // wave id == local agent id (0..3)
    const int l = t & 63;
    const int g = blockIdx.x * 4 + w;   // this wave's agent

    __shared__ __attribute__((aligned(16))) float w1s[320];
    __shared__ __attribute__((aligned(16))) float b1s[64];
    __shared__ __attribute__((aligned(16))) float b2s[128];
    __shared__ __attribute__((aligned(16))) float flat[4][160];   // 2.5 KB
    __shared__ __attribute__((aligned(16))) float maskv[4][32];   // 0.5 KB
    __shared__ __attribute__((aligned(16))) float featb[4][132];  // 2.1 KB
    __shared__ __attribute__((aligned(16))) float h1[4][2048];    // 32 KB
    // total ~40.0 KB -> 4 blocks/CU

    // ---- gather (wave-private; R13 layout: flat row-major [32][5])
    if (l < 32) {
        int j = (int)idx_in[g * TOPK + l];
        float4 sj  = ((const float4*)states)[j];
        float4 siv = ((const float4*)states)[g];
        float d0 = siv.x - sj.x;
        float d1 = siv.y - sj.y;
        float d2 = siv.z - sj.z;
        float d3 = siv.w - sj.w;
        flat[w][l * 5 + 0] = d0;
        flat[w][l * 5 + 1] = d1;
        flat[w][l * 5 + 2] = d2;
        flat[w][l * 5 + 3] = d3;
        flat[w][l * 5 + 4] = (j == g) ? 1.0f : 0.0f;
        float dist = sqrtf(__fadd_rn(__fmul_rn(d0, d0), __fmul_rn(d1, d1)));
        maskv[w][l] = (dist < 1.0f) ? 1.0f : 0.0f;
    } else if (l < 36) {
        int f = l - 32;
        float4 siv = ((const float4*)states)[g];
        float2 gi  = ((const float2*)goals)[g];
        float v = (f == 0) ? (siv.x - gi.x)
                : (f == 1) ? (siv.y - gi.y)
                : (f == 2) ? siv.z : siv.w;
        featb[w][128 + f] = v;
    }

    // ---- stage small weights (cross-wave -> the single barrier)
    for (int e = t; e < 320; e += 256) w1s[e] = W1[e];
    if (t < 64)  b1s[t] = b1[t];
    if (t < 128) b2s[t] = b2[t];
    __syncthreads();

    // ---- h1 (wave-private; R13 verbatim with a=w)
    #pragma unroll
    for (int u = 0; u < 32; ++u) {
        int e = u * 64 + l;
        int p = e & 31, o1 = e >> 5;
        float acc = b1s[o1];
        #pragma unroll
        for (int f = 0; f < 5; ++f)
            acc += w1s[o1 * 5 + f] * flat[w][f * 32 + p];
        h1[w][o1 * 32 + p] = fmaxf(acc, 0.0f);
    }

    // ---- h2: lane owns o in [ow*8,+8), p in [pt*8,+8); W2 from global w2t
    const int ow = l & 15;
    const int pt = l >> 4;
    float acc[8][8];
    #pragma unroll
    for (int k = 0; k < 8; ++k)
        #pragma unroll
        for (int q = 0; q < 8; ++q) acc[k][q] = 0.0f;

    for (int c4 = 0; c4 < 16; ++c4) {
        float4 wAv[4], wBv[4], hAv[4], hBv[4];
        #pragma unroll
        for (int cc = 0; cc < 4; ++cc) {
            int c = c4 * 4 + cc;
            wAv[cc] = *(const float4*)&w2t[c * 128 + ow * 8];      // W2[ow*8+0..3][c]
            wBv[cc] = *(const float4*)&w2t[c * 128 + ow * 8 + 4];  // W2[ow*8+4..7][c]
            hAv[cc] = *(const float4*)&h1[w][c * 32 + pt * 8];
            hBv[cc] = *(const float4*)&h1[w][c * 32 + pt * 8 + 4];
        }
        #pragma unroll
        for (int cc = 0; cc < 4; ++cc) {
            float wv[8] = {wAv[cc].x, wAv[cc].y, wAv[cc].z, wAv[cc].w,
                           wBv[cc].x, wBv[cc].y, wBv[cc].z, wBv[cc].w};
            float hv[8] = {hAv[cc].x, hAv[cc].y, hAv[cc].z, hAv[cc].w,
                           hBv[cc].x, hBv[cc].y, hBv[cc].z, hBv[cc].w};
            #pragma unroll
            for (int k = 0; k < 8; ++k)
                #pragma unroll
                for (int q = 0; q < 8; ++q)
                    acc[k][q] += wv[k] * hv[q];   // c ascending: R13 order
        }
    }

    // ---- bias + relu + mask + argmax (R13 verbatim with fa=w)
    float4 mA = *(const float4*)&maskv[w][pt * 8];
    float4 mB = *(const float4*)&maskv[w][pt * 8 + 4];
    float mv[8] = {mA.x, mA.y, mA.z, mA.w, mB.x, mB.y, mB.z, mB.w};
    #pragma unroll
    for (int k = 0; k < 8; ++k) {
        float bb = b2s[ow * 8 + k];
        unsigned long long best = 0ull;
        #pragma unroll
        for (int q = 0; q < 8; ++q) {
            float val = fmaxf(acc[k][q] + bb, 0.0f) * mv[q];
            unsigned long long key =
                ((unsigned long long)__float_as_uint(val) << 32)
                | (unsigned int)(31 - (pt * 8 + q));
            if (key > best) best = key;
        }
        unsigned long long o1 = __shfl_xor(best, 16, 64); if (o1 > best) best = o1;
        unsigned long long o2 = __shfl_xor(best, 32, 64); if (o2 > best) best = o2;
        if (pt == 0) {
            int pbest = 31 - (int)(best & 63ull);
            featb[w][ow * 8 + k] = (float)pbest;
        }
    }

    // ---- dense (wave-private; z-pool aliases own h1 region, now dead).
    //      R19 single-agent dense verbatim (PASSED).
    float* z1s = &h1[w][0];       // 64
    float* z2s = z1s + 64;        // 128
    float* z3s = z1s + 192;       // 64
    float* kvs = z1s + 256;       // 4

    {
        float a0 = bd1[l];
        for (int k = 0; k < 33; ++k) {
            float4 wv = *(const float4*)&Wd1[l * 132 + 4 * k];
            float4 f0 = *(const float4*)&featb[w][4 * k];
            a0 += wv.x * f0.x; a0 += wv.y * f0.y; a0 += wv.z * f0.z; a0 += wv.w * f0.w;
        }
        z1s[l] = fmaxf(a0, 0.0f);
    }

    {
        float accA = bd2[l];
        float accB = bd2[l + 64];
        for (int k = 0; k < 16; ++k) {
            float4 wa = *(const float4*)&Wd2[l * 64 + 4 * k];
            float4 wb = *(const float4*)&Wd2[(l + 64) * 64 + 4 * k];
            float4 f0 = *(const float4*)&z1s[4 * k];
            accA += wa.x * f0.x; accA += wa.y * f0.y;
            accA += wa.z * f0.z; accA += wa.w * f0.w;
            accB += wb.x * f0.x; accB += wb.y * f0.y;
            accB += wb.z * f0.z; accB += wb.w * f0.w;
        }
        z2s[l]      = fmaxf(accA, 0.0f);
        z2s[l + 64] = fmaxf(accB, 0.0f);
    }

    {
        float a0 = bd3[l];
        for (int k = 0; k < 32; ++k) {
            float4 wv = *(const float4*)&Wd3[l * 128 + 4 * k];
            float4 f0 = *(const float4*)&z2s[4 * k];
            a0 += wv.x * f0.x; a0 += wv.y * f0.y; a0 += wv.z * f0.z; a0 += wv.w * f0.w;
        }
        z3s[l] = fmaxf(a0, 0.0f);
    }

    if (l < 4) {
        float acc2 = bd4[l];
        for (int c = 0; c < 64; ++c) acc2 += Wd4[l * 64 + c] * z3s[c];
        kvs[l] = 2.0f / (1.0f + expf(-acc2)) + 0.2f;
    }
    if (l < 2) {
        float ka = kvs[2 * l + 0];
        float kb = kvs[2 * l + 1];
        float rel = featb[w][128 + l];
        float vel = featb[w][130 + l];
        out[g * 2 + l] = -(ka * rel + kb * vel);
    }
}

extern "C" void kernel_launch(void* const* d_in, const int* in_sizes, int n_in,
                              void* d_out, int out_size, void* d_ws, size_t ws_size,
                              hipStream_t stream)
{
    const float* states = (const float*)d_in[0];
    const float* goals  = (const float*)d_in[1];
    const float* W1  = (const float*)d_in[2];
    const float* b1  = (const float*)d_in[3];
    const float* W2  = (const float*)d_in[4];
    const float* b2  = (const float*)d_in[5];
    const float* Wd1 = (const float*)d_in[6];
    const float* bd1 = (const float*)d_in[7];
    const float* Wd2 = (const float*)d_in[8];
    const float* bd2 = (const float*)d_in[9];
    const float* Wd3 = (const float*)d_in[10];
    const float* bd3 = (const float*)d_in[11];
    const float* Wd4 = (const float*)d_in[12];
    const float* bd4 = (const float*)d_in[13];

    // workspace: u16 idx (256 KB) + W2^T (32 KB) -- fits the proven 512 KB
    unsigned short* idx = (unsigned short*)d_ws;
    float* w2t = (float*)((char*)d_ws + NAGENT * TOPK * sizeof(unsigned short));
    float* out = (float*)d_out;

    topk_kernel<<<NAGENT, 256, 0, stream>>>(states, W2, idx, w2t);
    fused_kernel<<<NAGENT / 4, 256, 0, stream>>>(states, goals, W1, b1, w2t, b2,
                                                 Wd1, bd1, Wd2, bd2, Wd3, bd3,
                                                 Wd4, bd4, idx, out);
}